// Round 2
// baseline (1489.581 us; speedup 1.0000x reference)
//
#include <hip/hip_runtime.h>
#include <hip/hip_bf16.h>
#include <stdint.h>

#define HW 262144          // 512*512
#define LDIM 33

typedef __bf16 bf16x8 __attribute__((ext_vector_type(8)));
typedef float  f32x4  __attribute__((ext_vector_type(4)));

union BF8 { bf16x8 v; unsigned u[4]; };

// LDS layout (bytes):
#define W1OFS 0        // 128 rows x 256B (128 bf16 ch-slots, 16B groups g ^ (row&15))
#define W2OFS 32768    // 64 rows x 256B, columns permuted by pi (see below)
#define W3OFS 49152    // 16 rows x 128B, columns permuted by pi2 (rows c>=3 zero)
#define B1OFS 51200    // 128 f32
#define B2OFS 51712    // 64 f32
#define SMBYTES 51968

__device__ __forceinline__ unsigned pk2(float a, float b) {
  __hip_bfloat162 h = __float22bfloat162_rn(make_float2(a, b));
  union { __hip_bfloat162 h; unsigned u; } c; c.h = h; return c.u;
}
__device__ __forceinline__ float tanh_fast(float x) {
  return 1.0f - 2.0f / (__expf(2.0f * x) + 1.0f);
}
__device__ __forceinline__ float gelu_t(float x) {
  float t = tanh_fast(0.7978845608028654f * (x + 0.044715f * x * x * x));
  return 0.5f * x * (1.0f + t);
}

__device__ __forceinline__ void issue_ctx(const float* __restrict__ cb0, float vr[4][8]) {
  #pragma unroll
  for (int ks = 0; ks < 4; ++ks)
    #pragma unroll
    for (int j = 0; j < 8; ++j)
      vr[ks][j] = cb0[(size_t)(ks * 32 + j) * HW];
}

// pi(s): s = 32*ks2 + 8*q + 4*jh + r  ->  f = 32*ks2 + 16*jh + 4*q + r
// (bijection on [0,128); same formula with s<64 for pi2). Weight columns are
// stored pi-permuted so GEMM2/GEMM3 B-fragments are each lane's OWN packed
// gelu outputs from the previous (transposed-layout) GEMM — no cross-lane.

__global__ __launch_bounds__(256, 3) void local3dlut_kernel(
    const float* __restrict__ img,  const float* __restrict__ ctx,
    const float* __restrict__ lut,  const float* __restrict__ W1,
    const float* __restrict__ b1,   const float* __restrict__ W2,
    const float* __restrict__ b2,   const float* __restrict__ W3,
    const float* __restrict__ b3,   const float* __restrict__ oscp,
    float* __restrict__ out)
{
  __shared__ uint4 smem4[SMBYTES / 16];
  char* sm = (char*)smem4;
  const int t    = threadIdx.x;
  const int lane = t & 63;
  const int wv   = t >> 6;
  const int n    = lane & 15;
  const int q    = lane >> 4;

  // ---- stage W1 (natural column order) ----
  #pragma unroll
  for (int rep = 0; rep < 16; ++rep) {
    int f4 = t + 256 * rep;                  // 0..4095
    float4 v = ((const float4*)W1)[f4];
    int fi = f4 << 2;
    int o = fi >> 7, k = fi & 127;
    char* dst = sm + W1OFS + o * 256 + (((k >> 3) ^ (o & 15)) << 4) + ((k & 7) << 1);
    *(uint2*)dst = make_uint2(pk2(v.x, v.y), pk2(v.z, v.w));
  }
  // ---- stage W2 with pi-permuted columns ----
  #pragma unroll
  for (int rep = 0; rep < 8; ++rep) {
    int idx = t + 256 * rep;                 // 0..2047 : (f2, g2, jh)
    int f2 = idx >> 5, rem = idx & 31, g2 = rem >> 1, jh = rem & 1;
    int f1b = 32 * (g2 >> 2) + 16 * jh + 4 * (g2 & 3);
    float4 v = *(const float4*)(W2 + f2 * 128 + f1b);
    char* dst = sm + W2OFS + f2 * 256 + ((g2 ^ (f2 & 15)) << 4) + jh * 8;
    *(uint2*)dst = make_uint2(pk2(v.x, v.y), pk2(v.z, v.w));
  }
  // ---- stage W3 (16 rows, c>=3 zero) with pi2-permuted columns ----
  {
    int c = t >> 4, rem = t & 15, g3 = rem >> 1, jh = rem & 1;
    int f2b = 32 * (g3 >> 2) + 16 * jh + 4 * (g3 & 3);
    float4 v = make_float4(0.f, 0.f, 0.f, 0.f);
    if (c < 3) v = *(const float4*)(W3 + c * 64 + f2b);
    char* dst = sm + W3OFS + c * 128 + ((g3 ^ (c & 7)) << 4) + jh * 8;
    *(uint2*)dst = make_uint2(pk2(v.x, v.y), pk2(v.z, v.w));
  }
  if (t < 128) ((float*)(sm + B1OFS))[t] = b1[t];
  if (t < 64)  ((float*)(sm + B2OFS))[t] = b2[t];
  __syncthreads();

  const float b3r[3] = { b3[0], b3[1], b3[2] };
  const float osc = oscp[0];

  const int p0   = blockIdx.x * 512;
  const int bi   = p0 >> 18;
  const int sblk = p0 & (HW - 1);
  const float* ctxB = ctx + (size_t)bi * ((size_t)128 * HW);
  const float* imgB = img + (size_t)bi * ((size_t)3 * HW);
  float*       outB = out + (size_t)bi * ((size_t)3 * HW);

  const size_t laneChOfs = (size_t)(q * 8) * HW;   // B-frag k rows = ch 32ks+8q+j

  float vr0[4][8], vr1[4][8];    // raw ctx floats for mt=0 / mt=1 (prefetched)
  {
    const int sw = sblk + wv * 32;
    issue_ctx(ctxB + laneChOfs + (sw + 0  + n), vr0);
    issue_ctx(ctxB + laneChOfs + (sw + 16 + n), vr1);
  }

  #pragma unroll 1
  for (int it = 0; it < 4; ++it) {
    const int sw = sblk + it * 128 + wv * 32;

    // ---- pack current ctx into B1-fragments (waits on loads) ----
    BF8 fr[2][4];
    #pragma unroll
    for (int ks = 0; ks < 4; ++ks) {
      #pragma unroll
      for (int i = 0; i < 4; ++i) {
        fr[0][ks].u[i] = pk2(vr0[ks][2 * i], vr0[ks][2 * i + 1]);
        fr[1][ks].u[i] = pk2(vr1[ks][2 * i], vr1[ks][2 * i + 1]);
      }
    }
    // ---- prefetch next iter, mt=0 (in flight across GEMM1/2) ----
    if (it < 3) {
      const int swn = sblk + (it + 1) * 128 + wv * 32;
      issue_ctx(ctxB + laneChOfs + (swn + n), vr0);
    }

    f32x4 acc2[4][2];
    #pragma unroll
    for (int n2 = 0; n2 < 4; ++n2)
      #pragma unroll
      for (int mt = 0; mt < 2; ++mt) { f32x4 z = {0.f,0.f,0.f,0.f}; acc2[n2][mt] = z; }

    #pragma unroll
    for (int h = 0; h < 2; ++h) {
      // GEMM1 (transposed): acc1[nf][mt] rows f=16(4h+nf)+4q+r, cols px=n+16mt
      f32x4 acc1[4][2];
      #pragma unroll
      for (int nf = 0; nf < 4; ++nf)
        #pragma unroll
        for (int mt = 0; mt < 2; ++mt) { f32x4 z = {0.f,0.f,0.f,0.f}; acc1[nf][mt] = z; }

      #pragma unroll
      for (int ks = 0; ks < 4; ++ks) {
        #pragma unroll
        for (int nf = 0; nf < 4; ++nf) {
          int row = (h * 4 + nf) * 16 + n;
          bf16x8 aw = *(const bf16x8*)(sm + W1OFS + row * 256 + ((((ks << 2) + q) ^ n) << 4));
          acc1[nf][0] = __builtin_amdgcn_mfma_f32_16x16x32_bf16(aw, fr[0][ks].v, acc1[nf][0], 0, 0, 0);
          acc1[nf][1] = __builtin_amdgcn_mfma_f32_16x16x32_bf16(aw, fr[1][ks].v, acc1[nf][1], 0, 0, 0);
        }
      }
      // bias + gelu -> packed pairs pd[nf][mt][rp] (bf16x2, r=2rp low / 2rp+1 high)
      unsigned pd[4][2][2];
      #pragma unroll
      for (int nf = 0; nf < 4; ++nf) {
        f32x4 bb = *(const f32x4*)(sm + B1OFS + (h * 64 + nf * 16 + 4 * q) * 4);
        #pragma unroll
        for (int mt = 0; mt < 2; ++mt) {
          float g0 = gelu_t(acc1[nf][mt][0] + bb[0]);
          float g1 = gelu_t(acc1[nf][mt][1] + bb[1]);
          float g2 = gelu_t(acc1[nf][mt][2] + bb[2]);
          float g3 = gelu_t(acc1[nf][mt][3] + bb[3]);
          pd[nf][mt][0] = pk2(g0, g1);
          pd[nf][mt][1] = pk2(g2, g3);
        }
      }
      // GEMM2 partial: B-frag = own pd regs (pi-permuted W2 columns)
      #pragma unroll
      for (int k2 = 0; k2 < 2; ++k2) {
        int ks2g = 2 * h + k2;
        BF8 bfr[2];
        #pragma unroll
        for (int mt = 0; mt < 2; ++mt) {
          bfr[mt].u[0] = pd[2 * k2][mt][0];     bfr[mt].u[1] = pd[2 * k2][mt][1];
          bfr[mt].u[2] = pd[2 * k2 + 1][mt][0]; bfr[mt].u[3] = pd[2 * k2 + 1][mt][1];
        }
        #pragma unroll
        for (int n2 = 0; n2 < 4; ++n2) {
          int row = n2 * 16 + n;
          bf16x8 aw = *(const bf16x8*)(sm + W2OFS + row * 256 + ((((ks2g << 2) + q) ^ n) << 4));
          acc2[n2][0] = __builtin_amdgcn_mfma_f32_16x16x32_bf16(aw, bfr[0].v, acc2[n2][0], 0, 0, 0);
          acc2[n2][1] = __builtin_amdgcn_mfma_f32_16x16x32_bf16(aw, bfr[1].v, acc2[n2][1], 0, 0, 0);
        }
      }
    }

    // ---- prefetch next iter, mt=1 ----
    if (it < 3) {
      const int swn = sblk + (it + 1) * 128 + wv * 32;
      issue_ctx(ctxB + laneChOfs + (swn + 16 + n), vr1);
    }

    // ---- layer2 bias+gelu -> pd2; GEMM3 with pi2-permuted W3 ----
    unsigned pd2[4][2][2];
    #pragma unroll
    for (int n2 = 0; n2 < 4; ++n2) {
      f32x4 bb = *(const f32x4*)(sm + B2OFS + (n2 * 16 + 4 * q) * 4);
      #pragma unroll
      for (int mt = 0; mt < 2; ++mt) {
        float g0 = gelu_t(acc2[n2][mt][0] + bb[0]);
        float g1 = gelu_t(acc2[n2][mt][1] + bb[1]);
        float g2 = gelu_t(acc2[n2][mt][2] + bb[2]);
        float g3 = gelu_t(acc2[n2][mt][3] + bb[3]);
        pd2[n2][mt][0] = pk2(g0, g1);
        pd2[n2][mt][1] = pk2(g2, g3);
      }
    }
    f32x4 acc3[2];
    { f32x4 z = {0.f,0.f,0.f,0.f}; acc3[0] = z; acc3[1] = z; }
    #pragma unroll
    for (int k3 = 0; k3 < 2; ++k3) {
      bf16x8 aw = *(const bf16x8*)(sm + W3OFS + n * 128 + ((((k3 << 2) + q) ^ (n & 7)) << 4));
      #pragma unroll
      for (int mt = 0; mt < 2; ++mt) {
        BF8 bfr;
        bfr.u[0] = pd2[2 * k3][mt][0];     bfr.u[1] = pd2[2 * k3][mt][1];
        bfr.u[2] = pd2[2 * k3 + 1][mt][0]; bfr.u[3] = pd2[2 * k3 + 1][mt][1];
        acc3[mt] = __builtin_amdgcn_mfma_f32_16x16x32_bf16(aw, bfr.v, acc3[mt], 0, 0, 0);
      }
    }

    // ---- spread offsets to 32 lanes (q=0 rows hold c=0..2), epilogue ----
    float oc[3];
    #pragma unroll
    for (int c = 0; c < 3; ++c) {
      float a0 = __shfl(acc3[0][c], n, 64);
      float a1 = __shfl(acc3[1][c], n, 64);
      oc[c] = (lane & 16) ? a1 : a0;
    }
    if (lane < 32) {
      const int sp = sw + lane;
      float ov[3];
      #pragma unroll
      for (int c = 0; c < 3; ++c) ov[c] = tanh_fast(oc[c] + b3r[c]) * osc;

      float rr = imgB[sp], gg = imgB[HW + sp], bb = imgB[2 * HW + sp];
      float gx = fminf(fmaxf((rr + 1.f) * 0.5f, 0.f), 1.f) * 32.f;
      float gy = fminf(fmaxf((gg + 1.f) * 0.5f, 0.f), 1.f) * 32.f;
      float gz = fminf(fmaxf((bb + 1.f) * 0.5f, 0.f), 1.f) * 32.f;
      int x0 = (int)gx, y0 = (int)gy, z0 = (int)gz;
      float fx = gx - (float)x0, fy = gy - (float)y0, fz = gz - (float)z0;
      int x1 = min(x0 + 1, 32), y1 = min(y0 + 1, 32), z1 = min(z0 + 1, 32);
      int zy00 = (z0 * LDIM + y0) * LDIM, zy01 = (z0 * LDIM + y1) * LDIM;
      int zy10 = (z1 * LDIM + y0) * LDIM, zy11 = (z1 * LDIM + y1) * LDIM;
      int i000 = (zy00 + x0) * 3, i001 = (zy00 + x1) * 3;
      int i010 = (zy01 + x0) * 3, i011 = (zy01 + x1) * 3;
      int i100 = (zy10 + x0) * 3, i101 = (zy10 + x1) * 3;
      int i110 = (zy11 + x0) * 3, i111 = (zy11 + x1) * 3;
      const float* L = lut;
      float so[3];
      #pragma unroll
      for (int ch = 0; ch < 3; ++ch) {
        float c000 = L[i000 + ch], c001 = L[i001 + ch];
        float c010 = L[i010 + ch], c011 = L[i011 + ch];
        float c100 = L[i100 + ch], c101 = L[i101 + ch];
        float c110 = L[i110 + ch], c111 = L[i111 + ch];
        float c00 = c000 + fx * (c001 - c000);
        float c01 = c010 + fx * (c011 - c010);
        float c10 = c100 + fx * (c101 - c100);
        float c11 = c110 + fx * (c111 - c110);
        float ca  = c00 + fy * (c01 - c00);
        float cb2 = c10 + fy * (c11 - c10);
        so[ch] = ca + fz * (cb2 - ca);
      }
      outB[sp]          = so[0] * 2.f - 1.f + ov[0];
      outB[HW + sp]     = so[1] * 2.f - 1.f + ov[1];
      outB[2 * HW + sp] = so[2] * 2.f - 1.f + ov[2];
    }
  }
}

extern "C" void kernel_launch(void* const* d_in, const int* in_sizes, int n_in,
                              void* d_out, int out_size, void* d_ws, size_t ws_size,
                              hipStream_t stream) {
  const float* img = (const float*)d_in[0];
  const float* ctx = (const float*)d_in[1];
  const float* lut = (const float*)d_in[2];
  const float* W1  = (const float*)d_in[3];
  const float* b1  = (const float*)d_in[4];
  const float* W2  = (const float*)d_in[5];
  const float* b2  = (const float*)d_in[6];
  const float* W3  = (const float*)d_in[7];
  const float* b3  = (const float*)d_in[8];
  const float* osc = (const float*)d_in[9];
  float* out = (float*)d_out;
  // 2048 blocks x 512 px; 256 thr (4 waves); 50.7 KB LDS -> 3 blocks/CU
  local3dlut_kernel<<<dim3(2048), dim3(256), 0, stream>>>(
      img, ctx, lut, W1, b1, W2, b2, W3, b3, osc, out);
}